// Round 7
// baseline (1107.238 us; speedup 1.0000x reference)
//
#include <hip/hip_runtime.h>
#include <math.h>

#define N_NODES 100000
#define N_EDGES 300000
#define N_GRAPHS 2048
#define HIDDEN 256
#define NODE_IN 64
#define N_LAYERS 3
#define LN_EPS 1e-5f
#define GTILE 32
#define N_TILES (N_NODES / GTILE)   // 3125
#define BCAP 256                    // bucket capacity per tile (mean 96, ~16 sigma)

typedef __attribute__((ext_vector_type(8))) short bf16x8;
typedef __attribute__((ext_vector_type(4))) float f32x4;

__device__ __forceinline__ float silu_f(float x) {
    return x / (1.f + expf(-x));
}

__device__ __forceinline__ short f2bf(float f) {
    union { float f; unsigned u; } v; v.f = f;
    unsigned r = v.u + 0x7fffu + ((v.u >> 16) & 1u);
    return (short)(r >> 16);
}

// Wtin[n][k] = bf16(Win[k][n]), n in [0,256), k in [0,64)
__global__ __launch_bounds__(256) void prep_win(
        const float* __restrict__ Win, short* __restrict__ Wtin) {
    const int n = threadIdx.x;
    for (int k = 0; k < NODE_IN; ++k)
        Wtin[n * NODE_IN + k] = f2bf(Win[k * HIDDEN + n]);
}

// Wt[l][n][k] = bf16(W[l][k][n])  -- so B-fragments are contiguous in k
__global__ __launch_bounds__(256) void prep_wt(
        const float* __restrict__ W, short* __restrict__ Wt) {
    const int l = blockIdx.x >> 8;
    const int n = blockIdx.x & 255;
    const int k = threadIdx.x;
    Wt[((size_t)l * 256 + n) * 256 + k] = f2bf(W[((size_t)l * 256 + k) * 256 + n]);
}

// h = silu(x @ W_in + b_in) via bf16 MFMA; 32 rows x 256 cols per block
__global__ __launch_bounds__(256) void input_proj_mfma(
        const float* __restrict__ x, const short* __restrict__ Wtin,
        const float* __restrict__ bin, float* __restrict__ h) {
    __shared__ __align__(16) char alds[GTILE * NODE_IN * 2];  // 4 KB bf16 A-tile
    const int t = threadIdx.x;
    const int b = blockIdx.x;

    // ---- stage: A = bf16(x-tile), XOR-swizzled ----
    const int srow = t >> 3;       // 0..31
    const int skg  = t & 7;        // 16B slot (8 bf16) within 64-k row
    const size_t xbase = ((size_t)b * GTILE + srow) * NODE_IN + skg * 8;
    float4 v0 = *reinterpret_cast<const float4*>(&x[xbase]);
    float4 v1 = *reinterpret_cast<const float4*>(&x[xbase + 4]);
    short a8[8];
    a8[0] = f2bf(v0.x); a8[1] = f2bf(v0.y); a8[2] = f2bf(v0.z); a8[3] = f2bf(v0.w);
    a8[4] = f2bf(v1.x); a8[5] = f2bf(v1.y); a8[6] = f2bf(v1.z); a8[7] = f2bf(v1.w);
    const int boff = srow * 128 + ((skg * 16) ^ ((srow & 7) << 4));
    *reinterpret_cast<bf16x8*>(alds + boff) = *reinterpret_cast<const bf16x8*>(a8);
    __syncthreads();

    // ---- MFMA: 2 row-tiles x 4 col-tiles per wave, K = 2 x 32 ----
    const int w  = t >> 6;
    const int l  = t & 63;
    const int lr = l & 15;
    const int g  = l >> 4;
    f32x4 acc[2][4] = {};
    #pragma unroll
    for (int kt = 0; kt < 2; ++kt) {
        const int aoff = (kt * 64 + g * 16) ^ ((lr & 7) << 4);
        bf16x8 a0 = *reinterpret_cast<const bf16x8*>(alds + lr * 128 + aoff);
        bf16x8 a1 = *reinterpret_cast<const bf16x8*>(alds + (16 + lr) * 128 + aoff);
        #pragma unroll
        for (int ct = 0; ct < 4; ++ct) {
            bf16x8 bf = *reinterpret_cast<const bf16x8*>(
                Wtin + (w * 64 + ct * 16 + lr) * NODE_IN + kt * 32 + g * 8);
            acc[0][ct] = __builtin_amdgcn_mfma_f32_16x16x32_bf16(a0, bf, acc[0][ct], 0, 0, 0);
            acc[1][ct] = __builtin_amdgcn_mfma_f32_16x16x32_bf16(a1, bf, acc[1][ct], 0, 0, 0);
        }
    }

    // ---- epilogue: h = silu(acc + bias) ----
    #pragma unroll
    for (int ct = 0; ct < 4; ++ct) {
        const int col = w * 64 + ct * 16 + lr;
        const float bs = bin[col];
        #pragma unroll
        for (int rt = 0; rt < 2; ++rt) {
            #pragma unroll
            for (int j = 0; j < 4; ++j) {
                const int row = rt * 16 + g * 4 + j;
                h[((size_t)b * GTILE + row) * HIDDEN + col] = silu_f(acc[rt][ct][j] + bs);
            }
        }
    }
}

// bucket edges by 32-row destination tile; entry = (dst&31)<<17 | src
__global__ __launch_bounds__(256) void build_buckets(
        const int* __restrict__ src, const int* __restrict__ dst,
        int* __restrict__ cnt, int* __restrict__ bucket) {
    const int e = blockIdx.x * 256 + threadIdx.x;
    if (e >= N_EDGES) return;
    const int d = dst[e];
    const int s = src[e];
    const int tile = d >> 5;
    const int slot = atomicAdd(&cnt[tile], 1);
    if (slot < BCAP) bucket[tile * BCAP + slot] = ((d & 31) << 17) | s;
}

// Fused per-layer kernel:
//   agg = h + sum_{edges into row} relu(h[src])   (full-wave gather, LDS f32 atomics)
//   out = silu(LN(agg @ W + b) * gamma + beta) + h   via bf16 MFMA
// 32 rows x 256 cols per block, 4 waves.
__global__ __launch_bounds__(256) void layer_fused(
        const float* __restrict__ h, const int* __restrict__ cnt,
        const int* __restrict__ bucket,
        const short* __restrict__ Wt, const float* __restrict__ bias,
        const float* __restrict__ gamma, const float* __restrict__ beta,
        float* __restrict__ out) {
    __shared__ float agg[GTILE][260];                    // 33.3 KB f32 (reused as h2)
    __shared__ __align__(16) char abf_lds[GTILE * 512];  // 16 KB bf16 A-tile (swizzled)
    __shared__ float mu_s[GTILE], rs_s[GTILE];
    __shared__ int ebuf[BCAP];

    const int t = threadIdx.x;
    const int b = blockIdx.x;
    const size_t base = (size_t)b * GTILE * HIDDEN;
    const int w = t >> 6;
    const int l = t & 63;

    const int c = min(cnt[b], BCAP);
    for (int i = t; i < c; i += 256) ebuf[i] = bucket[b * BCAP + i];

    // ---- init: agg[r][t] = h[r][t] (col t per thread); residual in regs ----
    float hres[GTILE];
    #pragma unroll
    for (int r = 0; r < GTILE; ++r) {
        float v = h[base + r * HIDDEN + t];
        hres[r] = v;
        agg[r][t] = v;
    }
    __syncthreads();   // ebuf + agg ready

    // ---- gather: each wave takes every 4th entry, all 64 lanes on one row ----
    for (int i = w; i < c; i += 4) {
        const int entry = ebuf[i];
        const int row = entry >> 17;
        const int s = entry & 0x1FFFF;
        const float* hp = &h[(size_t)s * HIDDEN];
        #pragma unroll
        for (int cc = 0; cc < 4; ++cc) {
            const float v = hp[cc * 64 + l];
            if (v > 0.f) atomicAdd(&agg[row][cc * 64 + l], v);
        }
    }
    __syncthreads();

    // ---- convert agg -> bf16 A-tile (XOR-swizzled 16B slots) ----
    {
        const int p  = t & 127;          // col pair (2p, 2p+1)
        const int r0 = (t >> 7) * 16;    // rows 0..15 or 16..31
        #pragma unroll
        for (int r = r0; r < r0 + 16; ++r) {
            const float lo = agg[r][2 * p];
            const float hi = agg[r][2 * p + 1];
            const unsigned packed =
                ((unsigned)(unsigned short)f2bf(hi) << 16) | (unsigned short)f2bf(lo);
            const int boff = r * 512 + ((4 * p) ^ ((r & 7) << 4));
            *reinterpret_cast<unsigned*>(abf_lds + boff) = packed;
        }
    }
    __syncthreads();

    // ---- MFMA: 2 row-tiles x 4 col-tiles per wave, K = 8 x 32 ----
    const int lr = l & 15;
    const int g  = l >> 4;
    f32x4 acc[2][4] = {};
    const short* wbase = Wt + (size_t)(w * 64 + lr) * 256 + g * 8;
    #pragma unroll
    for (int kt = 0; kt < 8; ++kt) {
        const int aoff = ((kt * 64 + g * 16) ^ ((lr & 7) << 4));
        bf16x8 a0 = *reinterpret_cast<const bf16x8*>(abf_lds + lr * 512 + aoff);
        bf16x8 a1 = *reinterpret_cast<const bf16x8*>(abf_lds + (16 + lr) * 512 + aoff);
        #pragma unroll
        for (int ct = 0; ct < 4; ++ct) {
            bf16x8 bf = *reinterpret_cast<const bf16x8*>(wbase + (size_t)ct * 16 * 256 + kt * 32);
            acc[0][ct] = __builtin_amdgcn_mfma_f32_16x16x32_bf16(a0, bf, acc[0][ct], 0, 0, 0);
            acc[1][ct] = __builtin_amdgcn_mfma_f32_16x16x32_bf16(a1, bf, acc[1][ct], 0, 0, 0);
        }
    }
    // (no barrier needed: h2 region (agg) is disjoint from abf_lds)

    // ---- write h2 = acc + bias into agg region ----
    float* h2 = &agg[0][0];
    #pragma unroll
    for (int ct = 0; ct < 4; ++ct) {
        const int col = w * 64 + ct * 16 + lr;
        const float bs = bias[col];
        #pragma unroll
        for (int rt = 0; rt < 2; ++rt) {
            #pragma unroll
            for (int j = 0; j < 4; ++j) {
                const int row = rt * 16 + g * 4 + j;
                h2[row * 260 + col] = acc[rt][ct][j] + bs;
            }
        }
    }
    __syncthreads();

    // ---- LN stats: 8 threads per row ----
    {
        const int n = t >> 3, j = t & 7;
        float s = 0.f;
        #pragma unroll
        for (int i = 0; i < HIDDEN / 8; ++i) s += h2[n * 260 + j + 8 * i];
        s += __shfl_xor(s, 1); s += __shfl_xor(s, 2); s += __shfl_xor(s, 4);
        const float mu = s * (1.f / HIDDEN);
        float v = 0.f;
        #pragma unroll
        for (int i = 0; i < HIDDEN / 8; ++i) {
            float d = h2[n * 260 + j + 8 * i] - mu;
            v += d * d;
        }
        v += __shfl_xor(v, 1); v += __shfl_xor(v, 2); v += __shfl_xor(v, 4);
        if (j == 0) {
            mu_s[n] = mu;
            rs_s[n] = rsqrtf(v * (1.f / HIDDEN) + LN_EPS);
        }
    }
    __syncthreads();

    // ---- epilogue: out[r][t] = silu(LN(h2[r][t])) + hres[r] (col t per thread) ----
    const float gm = gamma[t], bt = beta[t];
    #pragma unroll
    for (int r = 0; r < GTILE; ++r) {
        const float val = (h2[r * 260 + t] - mu_s[r]) * rs_s[r] * gm + bt;
        out[base + r * HIDDEN + t] = silu_f(val) + hres[r];
    }
}

// global mean pool over sorted batch_ids; one block per graph
__global__ __launch_bounds__(256) void pool_mean(
        const float* __restrict__ h, const int* __restrict__ bid,
        float* __restrict__ out) {
    const int g = blockIdx.x, t = threadIdx.x;
    int lo = 0, hi = N_NODES;
    while (lo < hi) { int mid = (lo + hi) >> 1; if (bid[mid] < g) lo = mid + 1; else hi = mid; }
    const int start = lo;
    hi = N_NODES;
    while (lo < hi) { int mid = (lo + hi) >> 1; if (bid[mid] < g + 1) lo = mid + 1; else hi = mid; }
    const int end = lo;
    float s = 0.f;
    for (int n = start; n < end; ++n) s += h[(size_t)n * HIDDEN + t];
    const float cnt = (float)(end - start);
    out[(size_t)g * HIDDEN + t] = s / fmaxf(cnt, 1.f);
}

extern "C" void kernel_launch(void* const* d_in, const int* in_sizes, int n_in,
                              void* d_out, int out_size, void* d_ws, size_t ws_size,
                              hipStream_t stream) {
    const float* x     = (const float*)d_in[0];
    const int*   ei    = (const int*)d_in[1];
    const int*   bid   = (const int*)d_in[2];
    const float* Win   = (const float*)d_in[3];
    const float* bin   = (const float*)d_in[4];
    const float* W     = (const float*)d_in[5];
    const float* b     = (const float*)d_in[6];
    const float* gamma = (const float*)d_in[7];
    const float* beta  = (const float*)d_in[8];
    float* out = (float*)d_out;

    const size_t hElems = (size_t)N_NODES * HIDDEN;
    float* A  = (float*)d_ws;
    float* B  = A + hElems;
    short* Wt = (short*)(B + hElems);
    int* cnt    = (int*)(Wt + (size_t)N_LAYERS * HIDDEN * HIDDEN);
    int* bucket = cnt + N_TILES;
    short* Wtin = (short*)(bucket + (size_t)N_TILES * BCAP);

    const int* src = ei;
    const int* dst = ei + N_EDGES;

    hipMemsetAsync(cnt, 0, N_TILES * sizeof(int), stream);
    build_buckets<<<(N_EDGES + 255) / 256, 256, 0, stream>>>(src, dst, cnt, bucket);
    prep_win<<<1, 256, 0, stream>>>(Win, Wtin);
    prep_wt<<<N_LAYERS * 256, 256, 0, stream>>>(W, Wt);
    input_proj_mfma<<<N_TILES, 256, 0, stream>>>(x, Wtin, bin, A);

    float* cur = A;
    float* alt = B;
    for (int l = 0; l < N_LAYERS; ++l) {
        layer_fused<<<N_TILES, 256, 0, stream>>>(
            cur, cnt, bucket, Wt + (size_t)l * HIDDEN * HIDDEN,
            b + (size_t)l * HIDDEN, gamma + (size_t)l * HIDDEN,
            beta + (size_t)l * HIDDEN, alt);
        float* tmp = cur; cur = alt; alt = tmp;
    }
    pool_mean<<<N_GRAPHS, 256, 0, stream>>>(cur, bid, out);
}

// Round 9
// 644.925 us; speedup vs baseline: 1.7168x; 1.7168x over previous
//
#include <hip/hip_runtime.h>
#include <math.h>

#define N_NODES 100000
#define N_EDGES 300000
#define N_GRAPHS 2048
#define HIDDEN 256
#define NODE_IN 64
#define N_LAYERS 3
#define LN_EPS 1e-5f
#define GTILE 32
#define N_TILES (N_NODES / GTILE)   // 3125
#define BCAP 256                    // bucket capacity per tile (mean 96, ~16 sigma)

typedef __attribute__((ext_vector_type(8))) short bf16x8;
typedef __attribute__((ext_vector_type(4))) float f32x4;

__device__ __forceinline__ float silu_f(float x) {
    return x / (1.f + expf(-x));
}

__device__ __forceinline__ short f2bf(float f) {
    union { float f; unsigned u; } v; v.f = f;
    unsigned r = v.u + 0x7fffu + ((v.u >> 16) & 1u);
    return (short)(r >> 16);
}

// Wtin[n][k] = bf16(Win[k][n]), n in [0,256), k in [0,64)
__global__ __launch_bounds__(256) void prep_win(
        const float* __restrict__ Win, short* __restrict__ Wtin) {
    const int n = threadIdx.x;
    for (int k = 0; k < NODE_IN; ++k)
        Wtin[n * NODE_IN + k] = f2bf(Win[k * HIDDEN + n]);
}

// Wt[l][n][k] = bf16(W[l][k][n])  -- so B-fragments are contiguous in k
__global__ __launch_bounds__(256) void prep_wt(
        const float* __restrict__ W, short* __restrict__ Wt) {
    const int l = blockIdx.x >> 8;
    const int n = blockIdx.x & 255;
    const int k = threadIdx.x;
    Wt[((size_t)l * 256 + n) * 256 + k] = f2bf(W[((size_t)l * 256 + k) * 256 + n]);
}

// h = silu(x @ W_in + b_in) via bf16 MFMA; 32 rows x 256 cols per block
__global__ __launch_bounds__(256) void input_proj_mfma(
        const float* __restrict__ x, const short* __restrict__ Wtin,
        const float* __restrict__ bin, float* __restrict__ h) {
    __shared__ __align__(16) char alds[GTILE * NODE_IN * 2];  // 4 KB bf16 A-tile
    const int t = threadIdx.x;
    const int b = blockIdx.x;

    const int srow = t >> 3;
    const int skg  = t & 7;
    const size_t xbase = ((size_t)b * GTILE + srow) * NODE_IN + skg * 8;
    float4 v0 = *reinterpret_cast<const float4*>(&x[xbase]);
    float4 v1 = *reinterpret_cast<const float4*>(&x[xbase + 4]);
    short a8[8];
    a8[0] = f2bf(v0.x); a8[1] = f2bf(v0.y); a8[2] = f2bf(v0.z); a8[3] = f2bf(v0.w);
    a8[4] = f2bf(v1.x); a8[5] = f2bf(v1.y); a8[6] = f2bf(v1.z); a8[7] = f2bf(v1.w);
    const int boff = srow * 128 + ((skg * 16) ^ ((srow & 7) << 4));
    *reinterpret_cast<bf16x8*>(alds + boff) = *reinterpret_cast<const bf16x8*>(a8);
    __syncthreads();

    const int w  = t >> 6;
    const int l  = t & 63;
    const int lr = l & 15;
    const int g  = l >> 4;
    f32x4 acc[2][4] = {};
    #pragma unroll
    for (int kt = 0; kt < 2; ++kt) {
        const int aoff = (kt * 64 + g * 16) ^ ((lr & 7) << 4);
        bf16x8 a0 = *reinterpret_cast<const bf16x8*>(alds + lr * 128 + aoff);
        bf16x8 a1 = *reinterpret_cast<const bf16x8*>(alds + (16 + lr) * 128 + aoff);
        #pragma unroll
        for (int ct = 0; ct < 4; ++ct) {
            bf16x8 bf = *reinterpret_cast<const bf16x8*>(
                Wtin + (w * 64 + ct * 16 + lr) * NODE_IN + kt * 32 + g * 8);
            acc[0][ct] = __builtin_amdgcn_mfma_f32_16x16x32_bf16(a0, bf, acc[0][ct], 0, 0, 0);
            acc[1][ct] = __builtin_amdgcn_mfma_f32_16x16x32_bf16(a1, bf, acc[1][ct], 0, 0, 0);
        }
    }

    #pragma unroll
    for (int ct = 0; ct < 4; ++ct) {
        const int col = w * 64 + ct * 16 + lr;
        const float bs = bin[col];
        #pragma unroll
        for (int rt = 0; rt < 2; ++rt) {
            #pragma unroll
            for (int j = 0; j < 4; ++j) {
                const int row = rt * 16 + g * 4 + j;
                h[((size_t)b * GTILE + row) * HIDDEN + col] = silu_f(acc[rt][ct][j] + bs);
            }
        }
    }
}

// ---- CSR-by-destination-row bucket build (3 passes, one-time) ----

// B1: per-node in-degree
__global__ __launch_bounds__(256) void count_rows(
        const int* __restrict__ dst, int* __restrict__ cnt32) {
    const int e = blockIdx.x * 256 + threadIdx.x;
    if (e >= N_EDGES) return;
    atomicAdd(&cnt32[dst[e]], 1);
}

// B2: per-tile exclusive scan of 32 row counts -> rowoff[33]; cursor in-place in cnt32
__global__ __launch_bounds__(64) void scan_rows(
        int* __restrict__ cnt32, int* __restrict__ rowoff) {
    const int tile = blockIdx.x;
    const int lane = threadIdx.x;
    if (lane < 32) {
        const int v = cnt32[tile * 32 + lane];
        int incl = v;
        #pragma unroll
        for (int d = 1; d < 32; d <<= 1) {
            const int u = __shfl_up(incl, d);
            if (lane >= d) incl += u;
        }
        const int excl = incl - v;
        rowoff[tile * 33 + lane] = excl;
        cnt32[tile * 32 + lane] = excl;       // becomes the scatter cursor
        if (lane == 31) rowoff[tile * 33 + 32] = incl;
    }
}

// B3: scatter src ids into row-sorted tile buckets
__global__ __launch_bounds__(256) void fill_bucket(
        const int* __restrict__ src, const int* __restrict__ dst,
        int* __restrict__ cursor, int* __restrict__ bucket) {
    const int e = blockIdx.x * 256 + threadIdx.x;
    if (e >= N_EDGES) return;
    const int d = dst[e];
    const int pos = atomicAdd(&cursor[d], 1);    // tile-relative offset
    if (pos < BCAP) bucket[(d >> 5) * BCAP + pos] = src[e];
}

// Fused per-layer kernel:
//   agg = h + sum_{edges into row} relu(h[src])   (per-row CSR span, register acc)
//   out = silu(LN(agg @ W + b) * gamma + beta) + h   via bf16 MFMA
__global__ __launch_bounds__(256) void layer_fused(
        const float* __restrict__ h, const int* __restrict__ rowoff,
        const int* __restrict__ bucket,
        const short* __restrict__ Wt, const float* __restrict__ bias,
        const float* __restrict__ gamma, const float* __restrict__ beta,
        float* __restrict__ out) {
    // union: A-tile bf16 [32][256] (16 KB, XOR-swizzled) then h2 f32 [32][260]
    __shared__ __align__(16) char smem[GTILE * 260 * 4];
    __shared__ float mu_s[GTILE], rs_s[GTILE];
    __shared__ int ebuf[BCAP];

    const int t = threadIdx.x;
    const int b = blockIdx.x;
    const size_t base = (size_t)b * GTILE * HIDDEN;

    const int srow = t >> 3;        // row within tile (8-lane group)
    const int scg  = t & 7;         // col group of 32

    const int total = min(rowoff[b * 33 + 32], BCAP);
    const int off0  = min(rowoff[b * 33 + srow], BCAP);
    const int off1  = min(rowoff[b * 33 + srow + 1], BCAP);
    for (int i = t; i < total; i += 256) ebuf[i] = bucket[b * BCAP + i];

    // ---- init: macc = h(self); residual kept in regs ----
    const size_t rowbase = base + (size_t)srow * HIDDEN + scg * 32;
    float hres[32];
    float macc[32];
    #pragma unroll
    for (int i = 0; i < 8; ++i) {
        float4 hv = *reinterpret_cast<const float4*>(&h[rowbase + i * 4]);
        hres[i * 4 + 0] = hv.x; hres[i * 4 + 1] = hv.y;
        hres[i * 4 + 2] = hv.z; hres[i * 4 + 3] = hv.w;
        macc[i * 4 + 0] = hv.x; macc[i * 4 + 1] = hv.y;
        macc[i * 4 + 2] = hv.z; macc[i * 4 + 3] = hv.w;
    }
    __syncthreads();   // ebuf ready

    // ---- gather: each 8-lane group walks only ITS row's span ----
    if (off0 < off1) {
        int s = ebuf[off0];
        for (int i = off0; i < off1; ) {
            const float* hp = &h[(size_t)s * HIDDEN + scg * 32];
            float4 v[8];
            #pragma unroll
            for (int j = 0; j < 8; ++j)
                v[j] = *reinterpret_cast<const float4*>(&hp[j * 4]);
            ++i;
            if (i < off1) s = ebuf[i];      // prefetch next id while loads in flight
            #pragma unroll
            for (int j = 0; j < 8; ++j) {
                macc[j * 4 + 0] += fmaxf(v[j].x, 0.f);
                macc[j * 4 + 1] += fmaxf(v[j].y, 0.f);
                macc[j * 4 + 2] += fmaxf(v[j].z, 0.f);
                macc[j * 4 + 3] += fmaxf(v[j].w, 0.f);
            }
        }
    }

    // ---- write bf16 A-tile (XOR-swizzled rows of 512B) ----
    #pragma unroll
    for (int j = 0; j < 4; ++j) {
        short abf[8];
        #pragma unroll
        for (int k = 0; k < 8; ++k) abf[k] = f2bf(macc[j * 8 + k]);
        const int boff = srow * 512 + ((scg * 64 + j * 16) ^ ((srow & 7) << 4));
        *reinterpret_cast<bf16x8*>(smem + boff) =
            *reinterpret_cast<const bf16x8*>(abf);
    }
    __syncthreads();

    // ---- MFMA: 2 row-tiles x 4 col-tiles per wave, K = 8 x 32 ----
    const int w  = t >> 6;
    const int l  = t & 63;
    const int lr = l & 15;
    const int g  = l >> 4;
    f32x4 acc[2][4] = {};
    const short* wbase = Wt + (size_t)(w * 64 + lr) * 256 + g * 8;
    #pragma unroll
    for (int kt = 0; kt < 8; ++kt) {
        const int aoff = ((kt * 64 + g * 16) ^ ((lr & 7) << 4));
        bf16x8 a0 = *reinterpret_cast<const bf16x8*>(smem + lr * 512 + aoff);
        bf16x8 a1 = *reinterpret_cast<const bf16x8*>(smem + (16 + lr) * 512 + aoff);
        #pragma unroll
        for (int ct = 0; ct < 4; ++ct) {
            bf16x8 bf = *reinterpret_cast<const bf16x8*>(wbase + (size_t)ct * 16 * 256 + kt * 32);
            acc[0][ct] = __builtin_amdgcn_mfma_f32_16x16x32_bf16(a0, bf, acc[0][ct], 0, 0, 0);
            acc[1][ct] = __builtin_amdgcn_mfma_f32_16x16x32_bf16(a1, bf, acc[1][ct], 0, 0, 0);
        }
    }
    __syncthreads();   // done reading A-tile; smem becomes h2 f32 [32][260]

    // ---- write h2 = acc + bias ----
    float* h2 = reinterpret_cast<float*>(smem);
    #pragma unroll
    for (int ct = 0; ct < 4; ++ct) {
        const int col = w * 64 + ct * 16 + lr;
        const float bs = bias[col];
        #pragma unroll
        for (int rt = 0; rt < 2; ++rt) {
            #pragma unroll
            for (int j = 0; j < 4; ++j) {
                const int row = rt * 16 + g * 4 + j;
                h2[row * 260 + col] = acc[rt][ct][j] + bs;
            }
        }
    }
    __syncthreads();

    // ---- LN stats: 8 threads per row ----
    {
        const int n = t >> 3, j = t & 7;
        float s = 0.f;
        #pragma unroll
        for (int i = 0; i < HIDDEN / 8; ++i) s += h2[n * 260 + j + 8 * i];
        s += __shfl_xor(s, 1); s += __shfl_xor(s, 2); s += __shfl_xor(s, 4);
        const float mu = s * (1.f / HIDDEN);
        float v = 0.f;
        #pragma unroll
        for (int i = 0; i < HIDDEN / 8; ++i) {
            float d = h2[n * 260 + j + 8 * i] - mu;
            v += d * d;
        }
        v += __shfl_xor(v, 1); v += __shfl_xor(v, 2); v += __shfl_xor(v, 4);
        if (j == 0) {
            mu_s[n] = mu;
            rs_s[n] = rsqrtf(v * (1.f / HIDDEN) + LN_EPS);
        }
    }
    __syncthreads();

    // ---- epilogue: out = silu(LN) + h ----
    const float mu = mu_s[srow], rs = rs_s[srow];
    #pragma unroll
    for (int i = 0; i < 8; ++i) {
        const int c0 = scg * 32 + i * 4;
        float4 gmv = *reinterpret_cast<const float4*>(&gamma[c0]);
        float4 btv = *reinterpret_cast<const float4*>(&beta[c0]);
        float4 o;
        o.x = silu_f((h2[srow * 260 + c0 + 0] - mu) * rs * gmv.x + btv.x) + hres[i * 4 + 0];
        o.y = silu_f((h2[srow * 260 + c0 + 1] - mu) * rs * gmv.y + btv.y) + hres[i * 4 + 1];
        o.z = silu_f((h2[srow * 260 + c0 + 2] - mu) * rs * gmv.z + btv.z) + hres[i * 4 + 2];
        o.w = silu_f((h2[srow * 260 + c0 + 3] - mu) * rs * gmv.w + btv.w) + hres[i * 4 + 3];
        *reinterpret_cast<float4*>(&out[rowbase + i * 4]) = o;
    }
}

// global mean pool over sorted batch_ids; one block per graph
__global__ __launch_bounds__(256) void pool_mean(
        const float* __restrict__ h, const int* __restrict__ bid,
        float* __restrict__ out) {
    const int g = blockIdx.x, t = threadIdx.x;
    int lo = 0, hi = N_NODES;
    while (lo < hi) { int mid = (lo + hi) >> 1; if (bid[mid] < g) lo = mid + 1; else hi = mid; }
    const int start = lo;
    hi = N_NODES;
    while (lo < hi) { int mid = (lo + hi) >> 1; if (bid[mid] < g + 1) lo = mid + 1; else hi = mid; }
    const int end = lo;
    float s = 0.f;
    for (int n = start; n < end; ++n) s += h[(size_t)n * HIDDEN + t];
    const float cnt = (float)(end - start);
    out[(size_t)g * HIDDEN + t] = s / fmaxf(cnt, 1.f);
}

extern "C" void kernel_launch(void* const* d_in, const int* in_sizes, int n_in,
                              void* d_out, int out_size, void* d_ws, size_t ws_size,
                              hipStream_t stream) {
    const float* x     = (const float*)d_in[0];
    const int*   ei    = (const int*)d_in[1];
    const int*   bid   = (const int*)d_in[2];
    const float* Win   = (const float*)d_in[3];
    const float* bin   = (const float*)d_in[4];
    const float* W     = (const float*)d_in[5];
    const float* b     = (const float*)d_in[6];
    const float* gamma = (const float*)d_in[7];
    const float* beta  = (const float*)d_in[8];
    float* out = (float*)d_out;

    const size_t hElems = (size_t)N_NODES * HIDDEN;
    float* A     = (float*)d_ws;
    float* B     = A + hElems;
    short* Wt    = (short*)(B + hElems);
    short* Wtin  = Wt + (size_t)N_LAYERS * HIDDEN * HIDDEN;
    int* cnt32   = (int*)(Wtin + HIDDEN * NODE_IN);     // per-node count -> cursor
    int* rowoff  = cnt32 + N_NODES;                     // 3125 * 33
    int* bucket  = rowoff + N_TILES * 33;               // 3125 * 256

    const int* src = ei;
    const int* dst = ei + N_EDGES;

    hipMemsetAsync(cnt32, 0, N_NODES * sizeof(int), stream);
    count_rows<<<(N_EDGES + 255) / 256, 256, 0, stream>>>(dst, cnt32);
    scan_rows<<<N_TILES, 64, 0, stream>>>(cnt32, rowoff);
    fill_bucket<<<(N_EDGES + 255) / 256, 256, 0, stream>>>(src, dst, cnt32, bucket);

    prep_win<<<1, 256, 0, stream>>>(Win, Wtin);
    prep_wt<<<N_LAYERS * 256, 256, 0, stream>>>(W, Wt);
    input_proj_mfma<<<N_TILES, 256, 0, stream>>>(x, Wtin, bin, A);

    float* cur = A;
    float* alt = B;
    for (int l = 0; l < N_LAYERS; ++l) {
        layer_fused<<<N_TILES, 256, 0, stream>>>(
            cur, rowoff, bucket, Wt + (size_t)l * HIDDEN * HIDDEN,
            b + (size_t)l * HIDDEN, gamma + (size_t)l * HIDDEN,
            beta + (size_t)l * HIDDEN, alt);
        float* tmp = cur; cur = alt; alt = tmp;
    }
    pool_mean<<<N_GRAPHS, 256, 0, stream>>>(cur, bid, out);
}

// Round 10
// 532.228 us; speedup vs baseline: 2.0804x; 1.2117x over previous
//
#include <hip/hip_runtime.h>
#include <math.h>

#define N_NODES 100000
#define N_EDGES 300000
#define N_GRAPHS 2048
#define HIDDEN 256
#define NODE_IN 64
#define N_LAYERS 3
#define LN_EPS 1e-5f
#define GTILE 32
#define N_TILES (N_NODES / GTILE)   // 3125
#define BCAP 256                    // bucket capacity per tile (mean 96, ~16 sigma)

typedef __attribute__((ext_vector_type(8))) short bf16x8;
typedef __attribute__((ext_vector_type(4))) float f32x4;

__device__ __forceinline__ float silu_f(float x) {
    return x / (1.f + expf(-x));
}

__device__ __forceinline__ short f2bf(float f) {
    union { float f; unsigned u; } v; v.f = f;
    unsigned r = v.u + 0x7fffu + ((v.u >> 16) & 1u);
    return (short)(r >> 16);
}

__device__ __forceinline__ float bf2f(short s) {
    union { unsigned u; float f; } v;
    v.u = ((unsigned)(unsigned short)s) << 16;
    return v.f;
}

// Wtin[n][k] = bf16(Win[k][n]), n in [0,256), k in [0,64)
__global__ __launch_bounds__(256) void prep_win(
        const float* __restrict__ Win, short* __restrict__ Wtin) {
    const int n = threadIdx.x;
    for (int k = 0; k < NODE_IN; ++k)
        Wtin[n * NODE_IN + k] = f2bf(Win[k * HIDDEN + n]);
}

// Wt[l][n][k] = bf16(W[l][k][n])  -- so B-fragments are contiguous in k
__global__ __launch_bounds__(256) void prep_wt(
        const float* __restrict__ W, short* __restrict__ Wt) {
    const int l = blockIdx.x >> 8;
    const int n = blockIdx.x & 255;
    const int k = threadIdx.x;
    Wt[((size_t)l * 256 + n) * 256 + k] = f2bf(W[((size_t)l * 256 + k) * 256 + n]);
}

// h(bf16) = silu(x @ W_in + b_in) via bf16 MFMA; 32 rows x 256 cols per block
__global__ __launch_bounds__(256) void input_proj_mfma(
        const float* __restrict__ x, const short* __restrict__ Wtin,
        const float* __restrict__ bin, short* __restrict__ h) {
    __shared__ __align__(16) char alds[GTILE * NODE_IN * 2];  // 4 KB bf16 A-tile
    const int t = threadIdx.x;
    const int b = blockIdx.x;

    const int srow = t >> 3;
    const int skg  = t & 7;
    const size_t xbase = ((size_t)b * GTILE + srow) * NODE_IN + skg * 8;
    float4 v0 = *reinterpret_cast<const float4*>(&x[xbase]);
    float4 v1 = *reinterpret_cast<const float4*>(&x[xbase + 4]);
    short a8[8];
    a8[0] = f2bf(v0.x); a8[1] = f2bf(v0.y); a8[2] = f2bf(v0.z); a8[3] = f2bf(v0.w);
    a8[4] = f2bf(v1.x); a8[5] = f2bf(v1.y); a8[6] = f2bf(v1.z); a8[7] = f2bf(v1.w);
    const int boff = srow * 128 + ((skg * 16) ^ ((srow & 7) << 4));
    *reinterpret_cast<bf16x8*>(alds + boff) = *reinterpret_cast<const bf16x8*>(a8);
    __syncthreads();

    const int w  = t >> 6;
    const int l  = t & 63;
    const int lr = l & 15;
    const int g  = l >> 4;
    f32x4 acc[2][4] = {};
    #pragma unroll
    for (int kt = 0; kt < 2; ++kt) {
        const int aoff = (kt * 64 + g * 16) ^ ((lr & 7) << 4);
        bf16x8 a0 = *reinterpret_cast<const bf16x8*>(alds + lr * 128 + aoff);
        bf16x8 a1 = *reinterpret_cast<const bf16x8*>(alds + (16 + lr) * 128 + aoff);
        #pragma unroll
        for (int ct = 0; ct < 4; ++ct) {
            bf16x8 bf = *reinterpret_cast<const bf16x8*>(
                Wtin + (w * 64 + ct * 16 + lr) * NODE_IN + kt * 32 + g * 8);
            acc[0][ct] = __builtin_amdgcn_mfma_f32_16x16x32_bf16(a0, bf, acc[0][ct], 0, 0, 0);
            acc[1][ct] = __builtin_amdgcn_mfma_f32_16x16x32_bf16(a1, bf, acc[1][ct], 0, 0, 0);
        }
    }

    #pragma unroll
    for (int ct = 0; ct < 4; ++ct) {
        const int col = w * 64 + ct * 16 + lr;
        const float bs = bin[col];
        #pragma unroll
        for (int rt = 0; rt < 2; ++rt) {
            #pragma unroll
            for (int j = 0; j < 4; ++j) {
                const int row = rt * 16 + g * 4 + j;
                h[((size_t)b * GTILE + row) * HIDDEN + col] = f2bf(silu_f(acc[rt][ct][j] + bs));
            }
        }
    }
}

// ---- CSR-by-destination-row bucket build (3 passes, one-time) ----

__global__ __launch_bounds__(256) void count_rows(
        const int* __restrict__ dst, int* __restrict__ cnt32) {
    const int e = blockIdx.x * 256 + threadIdx.x;
    if (e >= N_EDGES) return;
    atomicAdd(&cnt32[dst[e]], 1);
}

__global__ __launch_bounds__(64) void scan_rows(
        int* __restrict__ cnt32, int* __restrict__ rowoff) {
    const int tile = blockIdx.x;
    const int lane = threadIdx.x;
    if (lane < 32) {
        const int v = cnt32[tile * 32 + lane];
        int incl = v;
        #pragma unroll
        for (int d = 1; d < 32; d <<= 1) {
            const int u = __shfl_up(incl, d);
            if (lane >= d) incl += u;
        }
        const int excl = incl - v;
        rowoff[tile * 33 + lane] = excl;
        cnt32[tile * 32 + lane] = excl;       // becomes the scatter cursor
        if (lane == 31) rowoff[tile * 33 + 32] = incl;
    }
}

__global__ __launch_bounds__(256) void fill_bucket(
        const int* __restrict__ src, const int* __restrict__ dst,
        int* __restrict__ cursor, int* __restrict__ bucket) {
    const int e = blockIdx.x * 256 + threadIdx.x;
    if (e >= N_EDGES) return;
    const int d = dst[e];
    const int pos = atomicAdd(&cursor[d], 1);    // tile-relative offset
    if (pos < BCAP) bucket[(d >> 5) * BCAP + pos] = src[e];
}

// Fused per-layer kernel (h stored bf16):
//   agg = h + sum_{edges into row} relu(h[src])   (per-row CSR span, register acc)
//   out = silu(LN(agg @ W + b) * gamma + beta) + h   via bf16 MFMA
__global__ __launch_bounds__(256) void layer_fused(
        const short* __restrict__ h, const int* __restrict__ rowoff,
        const int* __restrict__ bucket,
        const short* __restrict__ Wt, const float* __restrict__ bias,
        const float* __restrict__ gamma, const float* __restrict__ beta,
        short* __restrict__ out) {
    // union: A-tile bf16 [32][256] (16 KB, XOR-swizzled) then h2 f32 [32][260]
    __shared__ __align__(16) char smem[GTILE * 260 * 4];
    __shared__ float mu_s[GTILE], rs_s[GTILE];
    __shared__ int ebuf[BCAP];

    const int t = threadIdx.x;
    const int b = blockIdx.x;
    const size_t base = (size_t)b * GTILE * HIDDEN;

    const int srow = t >> 3;        // row within tile (8-lane group)
    const int scg  = t & 7;         // col group of 32

    const int total = min(rowoff[b * 33 + 32], BCAP);
    const int off0  = min(rowoff[b * 33 + srow], BCAP);
    const int off1  = min(rowoff[b * 33 + srow + 1], BCAP);
    for (int i = t; i < total; i += 256) ebuf[i] = bucket[b * BCAP + i];

    // ---- init: macc = h(self); residual kept packed in regs ----
    const size_t rowbase = base + (size_t)srow * HIDDEN + scg * 32;
    bf16x8 hres[4];
    float macc[32];
    #pragma unroll
    for (int i = 0; i < 4; ++i) {
        hres[i] = *reinterpret_cast<const bf16x8*>(&h[rowbase + i * 8]);
        #pragma unroll
        for (int k = 0; k < 8; ++k) macc[i * 8 + k] = bf2f(hres[i][k]);
    }
    __syncthreads();   // ebuf ready

    // ---- gather: each 8-lane group walks its row's span, 2 entries deep ----
    {
        int i = off0;
        while (i + 1 < off1) {
            const int s0 = ebuf[i];
            const int s1 = ebuf[i + 1];
            const short* p0 = &h[(size_t)s0 * HIDDEN + scg * 32];
            const short* p1 = &h[(size_t)s1 * HIDDEN + scg * 32];
            bf16x8 u0[4], u1[4];
            #pragma unroll
            for (int j = 0; j < 4; ++j) u0[j] = *reinterpret_cast<const bf16x8*>(&p0[j * 8]);
            #pragma unroll
            for (int j = 0; j < 4; ++j) u1[j] = *reinterpret_cast<const bf16x8*>(&p1[j * 8]);
            #pragma unroll
            for (int j = 0; j < 4; ++j) {
                #pragma unroll
                for (int k = 0; k < 8; ++k) {
                    macc[j * 8 + k] += fmaxf(bf2f(u0[j][k]), 0.f) + fmaxf(bf2f(u1[j][k]), 0.f);
                }
            }
            i += 2;
        }
        if (i < off1) {
            const int s0 = ebuf[i];
            const short* p0 = &h[(size_t)s0 * HIDDEN + scg * 32];
            bf16x8 u0[4];
            #pragma unroll
            for (int j = 0; j < 4; ++j) u0[j] = *reinterpret_cast<const bf16x8*>(&p0[j * 8]);
            #pragma unroll
            for (int j = 0; j < 4; ++j) {
                #pragma unroll
                for (int k = 0; k < 8; ++k)
                    macc[j * 8 + k] += fmaxf(bf2f(u0[j][k]), 0.f);
            }
        }
    }

    // ---- write bf16 A-tile (XOR-swizzled rows of 512B) ----
    #pragma unroll
    for (int j = 0; j < 4; ++j) {
        short abf[8];
        #pragma unroll
        for (int k = 0; k < 8; ++k) abf[k] = f2bf(macc[j * 8 + k]);
        const int boff = srow * 512 + ((scg * 64 + j * 16) ^ ((srow & 7) << 4));
        *reinterpret_cast<bf16x8*>(smem + boff) =
            *reinterpret_cast<const bf16x8*>(abf);
    }
    __syncthreads();

    // ---- MFMA: 2 row-tiles x 4 col-tiles per wave, K = 8 x 32 ----
    const int w  = t >> 6;
    const int l  = t & 63;
    const int lr = l & 15;
    const int g  = l >> 4;
    f32x4 acc[2][4] = {};
    const short* wbase = Wt + (size_t)(w * 64 + lr) * 256 + g * 8;
    #pragma unroll
    for (int kt = 0; kt < 8; ++kt) {
        const int aoff = ((kt * 64 + g * 16) ^ ((lr & 7) << 4));
        bf16x8 a0 = *reinterpret_cast<const bf16x8*>(smem + lr * 512 + aoff);
        bf16x8 a1 = *reinterpret_cast<const bf16x8*>(smem + (16 + lr) * 512 + aoff);
        #pragma unroll
        for (int ct = 0; ct < 4; ++ct) {
            bf16x8 bf = *reinterpret_cast<const bf16x8*>(wbase + (size_t)ct * 16 * 256 + kt * 32);
            acc[0][ct] = __builtin_amdgcn_mfma_f32_16x16x32_bf16(a0, bf, acc[0][ct], 0, 0, 0);
            acc[1][ct] = __builtin_amdgcn_mfma_f32_16x16x32_bf16(a1, bf, acc[1][ct], 0, 0, 0);
        }
    }
    __syncthreads();   // done reading A-tile; smem becomes h2 f32 [32][260]

    // ---- write h2 = acc + bias ----
    float* h2 = reinterpret_cast<float*>(smem);
    #pragma unroll
    for (int ct = 0; ct < 4; ++ct) {
        const int col = w * 64 + ct * 16 + lr;
        const float bs = bias[col];
        #pragma unroll
        for (int rt = 0; rt < 2; ++rt) {
            #pragma unroll
            for (int j = 0; j < 4; ++j) {
                const int row = rt * 16 + g * 4 + j;
                h2[row * 260 + col] = acc[rt][ct][j] + bs;
            }
        }
    }
    __syncthreads();

    // ---- LN stats: 8 threads per row ----
    {
        const int n = t >> 3, j = t & 7;
        float s = 0.f;
        #pragma unroll
        for (int i = 0; i < HIDDEN / 8; ++i) s += h2[n * 260 + j + 8 * i];
        s += __shfl_xor(s, 1); s += __shfl_xor(s, 2); s += __shfl_xor(s, 4);
        const float mu = s * (1.f / HIDDEN);
        float v = 0.f;
        #pragma unroll
        for (int i = 0; i < HIDDEN / 8; ++i) {
            float d = h2[n * 260 + j + 8 * i] - mu;
            v += d * d;
        }
        v += __shfl_xor(v, 1); v += __shfl_xor(v, 2); v += __shfl_xor(v, 4);
        if (j == 0) {
            mu_s[n] = mu;
            rs_s[n] = rsqrtf(v * (1.f / HIDDEN) + LN_EPS);
        }
    }
    __syncthreads();

    // ---- epilogue: out = bf16(silu(LN) + h), coalesced bf16x8 stores ----
    const float mu = mu_s[srow], rs = rs_s[srow];
    #pragma unroll
    for (int i = 0; i < 4; ++i) {
        short o8[8];
        #pragma unroll
        for (int k = 0; k < 8; ++k) {
            const int c0 = scg * 32 + i * 8 + k;
            const float val = (h2[srow * 260 + c0] - mu) * rs * gamma[c0] + beta[c0];
            o8[k] = f2bf(silu_f(val) + bf2f(hres[i][k]));
        }
        *reinterpret_cast<bf16x8*>(&out[rowbase + i * 8]) =
            *reinterpret_cast<const bf16x8*>(o8);
    }
}

// global mean pool over sorted batch_ids; one block per graph; h is bf16
__global__ __launch_bounds__(256) void pool_mean(
        const short* __restrict__ h, const int* __restrict__ bid,
        float* __restrict__ out) {
    const int g = blockIdx.x, t = threadIdx.x;
    int lo = 0, hi = N_NODES;
    while (lo < hi) { int mid = (lo + hi) >> 1; if (bid[mid] < g) lo = mid + 1; else hi = mid; }
    const int start = lo;
    hi = N_NODES;
    while (lo < hi) { int mid = (lo + hi) >> 1; if (bid[mid] < g + 1) lo = mid + 1; else hi = mid; }
    const int end = lo;
    float s = 0.f;
    for (int n = start; n < end; ++n) s += bf2f(h[(size_t)n * HIDDEN + t]);
    const float cnt = (float)(end - start);
    out[(size_t)g * HIDDEN + t] = s / fmaxf(cnt, 1.f);
}

extern "C" void kernel_launch(void* const* d_in, const int* in_sizes, int n_in,
                              void* d_out, int out_size, void* d_ws, size_t ws_size,
                              hipStream_t stream) {
    const float* x     = (const float*)d_in[0];
    const int*   ei    = (const int*)d_in[1];
    const int*   bid   = (const int*)d_in[2];
    const float* Win   = (const float*)d_in[3];
    const float* bin   = (const float*)d_in[4];
    const float* W     = (const float*)d_in[5];
    const float* b     = (const float*)d_in[6];
    const float* gamma = (const float*)d_in[7];
    const float* beta  = (const float*)d_in[8];
    float* out = (float*)d_out;

    const size_t hElems = (size_t)N_NODES * HIDDEN;
    short* A     = (short*)d_ws;                        // bf16 h ping
    short* B     = A + hElems;                          // bf16 h pong
    short* Wt    = B + hElems;
    short* Wtin  = Wt + (size_t)N_LAYERS * HIDDEN * HIDDEN;
    int* cnt32   = (int*)(Wtin + HIDDEN * NODE_IN);     // per-node count -> cursor
    int* rowoff  = cnt32 + N_NODES;                     // 3125 * 33
    int* bucket  = rowoff + N_TILES * 33;               // 3125 * 256

    const int* src = ei;
    const int* dst = ei + N_EDGES;

    hipMemsetAsync(cnt32, 0, N_NODES * sizeof(int), stream);
    count_rows<<<(N_EDGES + 255) / 256, 256, 0, stream>>>(dst, cnt32);
    scan_rows<<<N_TILES, 64, 0, stream>>>(cnt32, rowoff);
    fill_bucket<<<(N_EDGES + 255) / 256, 256, 0, stream>>>(src, dst, cnt32, bucket);

    prep_win<<<1, 256, 0, stream>>>(Win, Wtin);
    prep_wt<<<N_LAYERS * 256, 256, 0, stream>>>(W, Wt);
    input_proj_mfma<<<N_TILES, 256, 0, stream>>>(x, Wtin, bin, A);

    short* cur = A;
    short* alt = B;
    for (int l = 0; l < N_LAYERS; ++l) {
        layer_fused<<<N_TILES, 256, 0, stream>>>(
            cur, rowoff, bucket, Wt + (size_t)l * HIDDEN * HIDDEN,
            b + (size_t)l * HIDDEN, gamma + (size_t)l * HIDDEN,
            beta + (size_t)l * HIDDEN, alt);
        short* tmp = cur; cur = alt; alt = tmp;
    }
    pool_mean<<<N_GRAPHS, 256, 0, stream>>>(cur, bid, out);
}